// Round 1
// baseline (466.360 us; speedup 1.0000x reference)
//
#include <hip/hip_runtime.h>

#define HD 64
#define ED 16
#define KC 65            // 64 k-rows + 1 bias row
#define MCOLS (KC*HD)    // 4160

static inline __device__ float bf2f(unsigned short u){
    union { unsigned int i; float f; } v; v.i = ((unsigned int)u) << 16; return v.f;
}
static inline __device__ unsigned short f2bf(float f){
    union { unsigned int i; float f; } v; v.f = f;
    unsigned int r = v.i + 0x7FFF + ((v.i >> 16) & 1);
    return (unsigned short)(r >> 16);
}

__global__ void k_zero2(int* a, int* b, int n){
    int i = blockIdx.x*blockDim.x + threadIdx.x;
    if(i < n){ a[i] = 0; b[i] = 0; }
}
__global__ void k_zerof(float* a, int n){
    int i = blockIdx.x*blockDim.x + threadIdx.x;
    if(i < n) a[i] = 0.f;
}
__global__ void k_deg(const int* __restrict__ src, const int* __restrict__ dst, int E,
                      int* __restrict__ degs, int* __restrict__ degd){
    int e = blockIdx.x*blockDim.x + threadIdx.x;
    if(e < E){ atomicAdd(&degs[src[e]], 1); atomicAdd(&degd[dst[e]], 1); }
}

// single-block scan: deg_src -> rowptr/cursor ; deg_dst -> countsf = max(deg,1)
__global__ void k_scan(const int* __restrict__ degs, const int* __restrict__ degd, int N,
                       int* __restrict__ rowptr, int* __restrict__ cursor, float* __restrict__ countsf){
    __shared__ int part[1024];
    int tid = threadIdx.x;
    int PER = (N + 1023) >> 10;           // 8 for N=8000
    int base = tid * PER;
    int local[16];
    int s = 0;
    for(int j = 0; j < PER; j++){
        int idx = base + j;
        int v = (idx < N) ? degs[idx] : 0;
        local[j] = s; s += v;
    }
    part[tid] = s;
    __syncthreads();
    for(int off = 1; off < 1024; off <<= 1){
        int v = (tid >= off) ? part[tid - off] : 0;
        __syncthreads();
        part[tid] += v;
        __syncthreads();
    }
    int prev = (tid == 0) ? 0 : part[tid - 1];
    for(int j = 0; j < PER; j++){
        int idx = base + j;
        if(idx < N){
            int r = prev + local[j];
            rowptr[idx] = r; cursor[idx] = r;
            int dd = degd[idx];
            countsf[idx] = (dd > 0) ? (float)dd : 1.0f;
        }
    }
    if(tid == 1023) rowptr[N] = prev + s;
}

__global__ void k_fill(const int* __restrict__ src, int E, int* __restrict__ cursor, int* __restrict__ elist){
    int e = blockIdx.x*blockDim.x + threadIdx.x;
    if(e < E){ int p = atomicAdd(&cursor[src[e]], 1); elist[p] = e; }
}

// h1 = relu(edge_attr @ W1 + b1) : E x 64
__global__ void k_h1(const float* __restrict__ ea, const float* __restrict__ W1,
                     const float* __restrict__ b1, int E, float* __restrict__ h1){
    __shared__ float s_ea[4][ED];
    int t = threadIdx.x;              // 256
    int o = t & 63, el = t >> 6;
    int e = blockIdx.x*4 + el;
    if(t < 4*ED){
        int ee = blockIdx.x*4 + t/ED;
        s_ea[t/ED][t%ED] = (ee < E) ? ea[(size_t)ee*ED + t%ED] : 0.f;
    }
    __syncthreads();
    if(e < E){
        float acc = b1[o];
        #pragma unroll
        for(int k = 0; k < ED; k++) acc += s_ea[el][k] * W1[k*HD + o];
        h1[(size_t)e*HD + o] = acc > 0.f ? acc : 0.f;
    }
}

// P[i][kc*64+o] = (kc<64) ? W2[kc][i*64+o] : b2[i*64+o]
__global__ void k_perm(const float* __restrict__ W2, const float* __restrict__ b2, float* __restrict__ P){
    int idx = blockIdx.x*blockDim.x + threadIdx.x;
    if(idx >= HD*MCOLS) return;
    int i = idx / MCOLS, c = idx % MCOLS;
    int kc = c >> 6, o = c & 63;
    P[idx] = (kc < HD) ? W2[(size_t)kc*(HD*HD) + i*HD + o] : b2[i*HD + o];
}

// transposed weights for coalesced GRU / root access
__global__ void k_wT(const float* __restrict__ w_ih, const float* __restrict__ w_hh,
                     const float* __restrict__ Wroot,
                     float* __restrict__ wTih, float* __restrict__ wThh, float* __restrict__ wrT){
    int idx = blockIdx.x*blockDim.x + threadIdx.x;
    if(idx < 3*HD*HD){
        int g = idx / HD, i = idx % HD;
        wTih[i*3*HD + g] = w_ih[idx];
        wThh[i*3*HD + g] = w_hh[idx];
    }
    if(idx < HD*HD){
        int o = idx / HD, i = idx % HD;
        wrT[i*HD + o] = Wroot[idx];
    }
}

// M[nloc][c] = sum_i state[c0+nloc][i] * P[i][c], bf16 out.  grid=(65, cn/32), block=256
__global__ void k_gemm_M(const float* __restrict__ state, const float* __restrict__ P,
                         int c0, unsigned short* __restrict__ M){
    __shared__ float s_st[64*40];                 // [i][nloc] stride 40
    int tid = threadIdx.x;
    int n0 = blockIdx.y * 32;                     // chunk-local
    int c  = blockIdx.x * 64 + (tid & 63);
    int sg = tid >> 6;
    #pragma unroll
    for(int r = 0; r < 8; r++){
        int idx = tid + r*256;
        int nloc = idx >> 6, i = idx & 63;
        s_st[i*40 + nloc] = state[(size_t)(c0 + n0 + nloc)*HD + i];
    }
    __syncthreads();
    float acc[8];
    #pragma unroll
    for(int a = 0; a < 8; a++) acc[a] = 0.f;
    const float* Pc = P + c;
    #pragma unroll 4
    for(int i = 0; i < HD; i++){
        float p = Pc[(size_t)i*MCOLS];
        const float4* q = (const float4*)&s_st[i*40 + sg*8];
        float4 q0 = q[0], q1 = q[1];
        acc[0] += q0.x*p; acc[1] += q0.y*p; acc[2] += q0.z*p; acc[3] += q0.w*p;
        acc[4] += q1.x*p; acc[5] += q1.y*p; acc[6] += q1.z*p; acc[7] += q1.w*p;
    }
    unsigned short* Mr = M + (size_t)(n0 + sg*8)*MCOLS + c;
    #pragma unroll
    for(int a = 0; a < 8; a++) Mr[(size_t)a*MCOLS] = f2bf(acc[a]);
}

// per-src block: stage M[s] in LDS, loop out-edges, scatter msg into agg via atomics. block=64
__global__ void k_msg_scatter(int c0, const int* __restrict__ rowptr, const int* __restrict__ elist,
                              const int* __restrict__ dstarr, const float* __restrict__ h1,
                              const unsigned short* __restrict__ M, float* __restrict__ agg){
    int s = c0 + blockIdx.x;
    int beg = rowptr[s], end = rowptr[s+1];
    if(beg == end) return;
    __shared__ uint4 s_Mv[MCOLS/8];               // 4160 u16 = 520 uint4
    __shared__ float s_h1[HD];
    unsigned short* s_M = (unsigned short*)s_Mv;
    int tid = threadIdx.x;                        // 64
    {
        const uint4* srcl = (const uint4*)(M + (size_t)(s - c0)*MCOLS);
        for(int it = tid; it < MCOLS/8; it += 64) s_Mv[it] = srcl[it];
    }
    __syncthreads();
    float bias = bf2f(s_M[HD*HD + tid]);
    for(int p = beg; p < end; p++){
        int e = elist[p];
        s_h1[tid] = h1[(size_t)e*HD + tid];
        __syncthreads();
        float a0 = 0, a1 = 0, a2 = 0, a3 = 0;
        #pragma unroll
        for(int k = 0; k < HD; k += 4){
            a0 += s_h1[k]   * bf2f(s_M[(k  )*HD + tid]);
            a1 += s_h1[k+1] * bf2f(s_M[(k+1)*HD + tid]);
            a2 += s_h1[k+2] * bf2f(s_M[(k+2)*HD + tid]);
            a3 += s_h1[k+3] * bf2f(s_M[(k+3)*HD + tid]);
        }
        float msg = (a0 + a1) + (a2 + a3) + bias;
        int d = dstarr[e];
        atomicAdd(&agg[(size_t)d*HD + tid], msg);
        __syncthreads();
    }
}

// m = relu(agg/counts + state @ Wroot^T + b_conv). block=64, grid=N
__global__ void k_m(const float* __restrict__ agg, const float* __restrict__ countsf,
                    const float* __restrict__ state, const float* __restrict__ wrT,
                    const float* __restrict__ bconv, float* __restrict__ mbuf){
    int d = blockIdx.x;
    int o = threadIdx.x;
    __shared__ float s_x[HD];
    s_x[o] = state[(size_t)d*HD + o];
    __syncthreads();
    float root = bconv[o];
    #pragma unroll 8
    for(int i = 0; i < HD; i++) root += s_x[i] * wrT[i*HD + o];
    float m = agg[(size_t)d*HD + o] / countsf[d] + root;
    mbuf[(size_t)d*HD + o] = m > 0.f ? m : 0.f;
}

// GRU cell, 4 nodes/block, block=192 (= 3h gate outputs)
__global__ void k_gru(const float* __restrict__ mbuf, const float* __restrict__ hprev,
                      const float* __restrict__ wTih, const float* __restrict__ wThh,
                      const float* __restrict__ b_ih, const float* __restrict__ b_hh,
                      float* __restrict__ hnew){
    int d0 = blockIdx.x * 4;
    int t = threadIdx.x;                          // 192
    __shared__ float s_m[4*HD], s_h[4*HD], s_gi[4*192], s_gh[4*192];
    for(int idx = t; idx < 4*HD; idx += 192){
        s_m[idx] = mbuf[(size_t)d0*HD + idx];
        s_h[idx] = hprev[(size_t)d0*HD + idx];
    }
    __syncthreads();
    float gi0 = b_ih[t], gi1 = gi0, gi2 = gi0, gi3 = gi0;
    float gh0 = b_hh[t], gh1 = gh0, gh2 = gh0, gh3 = gh0;
    #pragma unroll 4
    for(int i = 0; i < HD; i++){
        float wi = wTih[i*192 + t];
        float wh = wThh[i*192 + t];
        gi0 += s_m[i]*wi;      gh0 += s_h[i]*wh;
        gi1 += s_m[HD+i]*wi;   gh1 += s_h[HD+i]*wh;
        gi2 += s_m[2*HD+i]*wi; gh2 += s_h[2*HD+i]*wh;
        gi3 += s_m[3*HD+i]*wi; gh3 += s_h[3*HD+i]*wh;
    }
    s_gi[t] = gi0; s_gi[192+t] = gi1; s_gi[384+t] = gi2; s_gi[576+t] = gi3;
    s_gh[t] = gh0; s_gh[192+t] = gh1; s_gh[384+t] = gh2; s_gh[576+t] = gh3;
    __syncthreads();
    for(int idx = t; idx < 4*HD; idx += 192){
        int nl = idx >> 6, j = idx & 63;
        const float* gi = s_gi + nl*192;
        const float* gh = s_gh + nl*192;
        float r  = 1.f/(1.f + __expf(-(gi[j]      + gh[j])));
        float z  = 1.f/(1.f + __expf(-(gi[HD+j]   + gh[HD+j])));
        float nn = tanhf(gi[2*HD+j] + r*gh[2*HD+j]);
        hnew[(size_t)d0*HD + idx] = (1.f - z)*nn + z*s_h[idx];
    }
}

extern "C" void kernel_launch(void* const* d_in, const int* in_sizes, int n_in,
                              void* d_out, int out_size, void* d_ws, size_t ws_size,
                              hipStream_t stream){
    const float* x     = (const float*)d_in[0];
    const float* ea    = (const float*)d_in[1];
    const float* W1    = (const float*)d_in[2];
    const float* b1    = (const float*)d_in[3];
    const float* W2    = (const float*)d_in[4];
    const float* b2    = (const float*)d_in[5];
    const float* Wroot = (const float*)d_in[6];
    const float* bconv = (const float*)d_in[7];
    const float* w_ih  = (const float*)d_in[8];
    const float* w_hh  = (const float*)d_in[9];
    const float* b_ih  = (const float*)d_in[10];
    const float* b_hh  = (const float*)d_in[11];
    const int*   eidx  = (const int*)d_in[12];
    int N = in_sizes[0] / HD;
    int E = in_sizes[1] / ED;
    const int* srcarr = eidx;
    const int* dstarr = eidx + E;

    char* w = (char*)d_ws;
    size_t off = 0;
    auto alloc = [&](size_t bytes)->char*{
        char* p = w + off; off = (off + bytes + 255) & ~(size_t)255; return p;
    };
    int*   deg_src = (int*)alloc((size_t)N*4);
    int*   deg_dst = (int*)alloc((size_t)N*4);
    int*   rowptr  = (int*)alloc((size_t)(N+1)*4);
    int*   cursor  = (int*)alloc((size_t)N*4);
    int*   elist   = (int*)alloc((size_t)E*4);
    float* countsf = (float*)alloc((size_t)N*4);
    float* h1      = (float*)alloc((size_t)E*HD*4);
    float* P       = (float*)alloc((size_t)HD*MCOLS*4);
    float* wTih    = (float*)alloc((size_t)3*HD*HD*4);
    float* wThh    = (float*)alloc((size_t)3*HD*HD*4);
    float* wrT     = (float*)alloc((size_t)HD*HD*4);
    float* agg     = (float*)alloc((size_t)N*HD*4);
    float* mbuf    = (float*)alloc((size_t)N*HD*4);
    float* stA     = (float*)alloc((size_t)N*HD*4);
    float* stB     = (float*)alloc((size_t)N*HD*4);
    // remaining workspace -> bf16 M chunk (node-chunked if ws is small)
    size_t avail = (ws_size > off) ? ws_size - off : 0;
    long long Cll = (long long)(avail / ((size_t)MCOLS*2));
    int C = (Cll > N) ? N : (int)Cll;
    C &= ~31;
    if(C < 32) C = 32;
    unsigned short* M = (unsigned short*)(w + off);

    // ---- precompute ----
    hipLaunchKernelGGL(k_zero2, dim3((N+255)/256), dim3(256), 0, stream, deg_src, deg_dst, N);
    hipLaunchKernelGGL(k_deg,   dim3((E+255)/256), dim3(256), 0, stream, srcarr, dstarr, E, deg_src, deg_dst);
    hipLaunchKernelGGL(k_scan,  dim3(1), dim3(1024), 0, stream, deg_src, deg_dst, N, rowptr, cursor, countsf);
    hipLaunchKernelGGL(k_fill,  dim3((E+255)/256), dim3(256), 0, stream, srcarr, E, cursor, elist);
    hipLaunchKernelGGL(k_h1,    dim3((E+3)/4), dim3(256), 0, stream, ea, W1, b1, E, h1);
    hipLaunchKernelGGL(k_perm,  dim3((HD*MCOLS+255)/256), dim3(256), 0, stream, W2, b2, P);
    hipLaunchKernelGGL(k_wT,    dim3((3*HD*HD+255)/256), dim3(256), 0, stream, w_ih, w_hh, Wroot, wTih, wThh, wrT);

    // ---- 3 message-passing + GRU iterations ----
    const float* state = x;
    for(int it = 0; it < 3; ++it){
        hipLaunchKernelGGL(k_zerof, dim3((N*HD+255)/256), dim3(256), 0, stream, agg, N*HD);
        for(int c0 = 0; c0 < N; c0 += C){
            int cn = (N - c0 < C) ? (N - c0) : C;
            hipLaunchKernelGGL(k_gemm_M, dim3(65, cn/32), dim3(256), 0, stream, state, P, c0, M);
            hipLaunchKernelGGL(k_msg_scatter, dim3(cn), dim3(64), 0, stream,
                               c0, rowptr, elist, dstarr, h1, M, agg);
        }
        hipLaunchKernelGGL(k_m, dim3(N), dim3(64), 0, stream, agg, countsf, state, wrT, bconv, mbuf);
        float* outp = (it == 2) ? (float*)d_out : ((it == 0) ? stA : stB);
        hipLaunchKernelGGL(k_gru, dim3(N/4), dim3(192), 0, stream,
                           mbuf, state, wTih, wThh, b_ih, b_hh, outp);
        state = outp;
    }
}

// Round 2
// 325.489 us; speedup vs baseline: 1.4328x; 1.4328x over previous
//
#include <hip/hip_runtime.h>

#define HD 64
#define ED 16
#define KC 65            // 64 k-rows + 1 bias row
#define MCOLS (KC*HD)    // 4160

typedef __bf16 bf16x8 __attribute__((ext_vector_type(8)));
typedef float  f32x4  __attribute__((ext_vector_type(4)));

static inline __device__ float bf2f(unsigned short u){
    union { unsigned int i; float f; } v; v.i = ((unsigned int)u) << 16; return v.f;
}
static inline __device__ unsigned short f2bf(float f){
    union { unsigned int i; float f; } v; v.f = f;
    unsigned int r = v.i + 0x7FFF + ((v.i >> 16) & 1);
    return (unsigned short)(r >> 16);
}

__global__ void k_zero2(int* a, int* b, int n){
    int i = blockIdx.x*blockDim.x + threadIdx.x;
    if(i < n){ a[i] = 0; b[i] = 0; }
}
__global__ void k_zerof(float* a, int n){
    int i = blockIdx.x*blockDim.x + threadIdx.x;
    if(i < n) a[i] = 0.f;
}
__global__ void k_deg(const int* __restrict__ src, const int* __restrict__ dst, int E,
                      int* __restrict__ degs, int* __restrict__ degd){
    int e = blockIdx.x*blockDim.x + threadIdx.x;
    if(e < E){ atomicAdd(&degs[src[e]], 1); atomicAdd(&degd[dst[e]], 1); }
}

// single-block scan: deg_src -> rowptr/cursor ; deg_dst -> countsf = max(deg,1)
__global__ void k_scan(const int* __restrict__ degs, const int* __restrict__ degd, int N,
                       int* __restrict__ rowptr, int* __restrict__ cursor, float* __restrict__ countsf){
    __shared__ int part[1024];
    int tid = threadIdx.x;
    int PER = (N + 1023) >> 10;           // 8 for N=8000
    int base = tid * PER;
    int local[16];
    int s = 0;
    for(int j = 0; j < PER; j++){
        int idx = base + j;
        int v = (idx < N) ? degs[idx] : 0;
        local[j] = s; s += v;
    }
    part[tid] = s;
    __syncthreads();
    for(int off = 1; off < 1024; off <<= 1){
        int v = (tid >= off) ? part[tid - off] : 0;
        __syncthreads();
        part[tid] += v;
        __syncthreads();
    }
    int prev = (tid == 0) ? 0 : part[tid - 1];
    for(int j = 0; j < PER; j++){
        int idx = base + j;
        if(idx < N){
            int r = prev + local[j];
            rowptr[idx] = r; cursor[idx] = r;
            int dd = degd[idx];
            countsf[idx] = (dd > 0) ? (float)dd : 1.0f;
        }
    }
    if(tid == 1023) rowptr[N] = prev + s;
}

__global__ void k_fill(const int* __restrict__ src, int E, int* __restrict__ cursor, int* __restrict__ elist){
    int e = blockIdx.x*blockDim.x + threadIdx.x;
    if(e < E){ int p = atomicAdd(&cursor[src[e]], 1); elist[p] = e; }
}

// h1 = relu(edge_attr @ W1 + b1) : E x 64
__global__ void k_h1(const float* __restrict__ ea, const float* __restrict__ W1,
                     const float* __restrict__ b1, int E, float* __restrict__ h1){
    __shared__ float s_ea[4][ED];
    int t = threadIdx.x;              // 256
    int o = t & 63, el = t >> 6;
    int e = blockIdx.x*4 + el;
    if(t < 4*ED){
        int ee = blockIdx.x*4 + t/ED;
        s_ea[t/ED][t%ED] = (ee < E) ? ea[(size_t)ee*ED + t%ED] : 0.f;
    }
    __syncthreads();
    if(e < E){
        float acc = b1[o];
        #pragma unroll
        for(int k = 0; k < ED; k++) acc += s_ea[el][k] * W1[k*HD + o];
        h1[(size_t)e*HD + o] = acc > 0.f ? acc : 0.f;
    }
}

// PT[c][i] = bf16( c=kc*64+o : kc<64 ? W2[kc][i*64+o] : b2[i*64+o] )   (4160 x 64)
__global__ void k_permT(const float* __restrict__ W2, const float* __restrict__ b2,
                        unsigned short* __restrict__ PT){
    int idx = blockIdx.x*blockDim.x + threadIdx.x;
    if(idx >= MCOLS*HD) return;
    int c = idx / HD, i = idx % HD;
    int kc = c >> 6, o = c & 63;
    float v = (kc < HD) ? W2[(size_t)kc*(HD*HD) + i*HD + o] : b2[i*HD + o];
    PT[idx] = f2bf(v);
}

// transposed weights for coalesced GRU / root access
__global__ void k_wT(const float* __restrict__ w_ih, const float* __restrict__ w_hh,
                     const float* __restrict__ Wroot,
                     float* __restrict__ wTih, float* __restrict__ wThh, float* __restrict__ wrT){
    int idx = blockIdx.x*blockDim.x + threadIdx.x;
    if(idx < 3*HD*HD){
        int g = idx / HD, i = idx % HD;
        wTih[i*3*HD + g] = w_ih[idx];
        wThh[i*3*HD + g] = w_hh[idx];
    }
    if(idx < HD*HD){
        int o = idx / HD, i = idx % HD;
        wrT[i*HD + o] = Wroot[idx];
    }
}

// state (n x 64 f32) -> bf16 copy
__global__ void k_cvtA(const float* __restrict__ s, unsigned short* __restrict__ a, int n){
    int i = (blockIdx.x*blockDim.x + threadIdx.x) * 4;
    if(i < n){
        float4 v = *(const float4*)&s[i];
        ushort4 o;
        o.x = f2bf(v.x); o.y = f2bf(v.y); o.z = f2bf(v.z); o.w = f2bf(v.w);
        *(ushort4*)&a[i] = o;
    }
}

// MFMA GEMM: M[nloc][c] = sum_i Abf[c0+nloc][i] * PT[c][i], bf16 out.
// grid=(65, cn/32), block=64 (1 wave). Per wave: 32 rows x 64 cols, K=64.
__global__ void k_gemm_mfma(const unsigned short* __restrict__ Abf,
                            const unsigned short* __restrict__ PT,
                            int c0, unsigned short* __restrict__ M){
    int lane = threadIdx.x;           // 0..63
    int r = lane & 15, g = lane >> 4; // g = k-group (8 k's each)
    int wcol = blockIdx.x * 64;
    int nbase = blockIdx.y * 32;      // chunk-local row base
    f32x4 acc[2][4];
    #pragma unroll
    for(int a = 0; a < 2; a++)
        #pragma unroll
        for(int b = 0; b < 4; b++) acc[a][b] = (f32x4){0.f,0.f,0.f,0.f};

    bf16x8 afr[2][2];   // [rb][ks]
    bf16x8 bfr[4][2];   // [cb][ks]
    #pragma unroll
    for(int rb = 0; rb < 2; rb++)
        #pragma unroll
        for(int ks = 0; ks < 2; ks++)
            afr[rb][ks] = *(const bf16x8*)&Abf[(size_t)(c0 + nbase + rb*16 + r)*HD + ks*32 + g*8];
    #pragma unroll
    for(int cb = 0; cb < 4; cb++)
        #pragma unroll
        for(int ks = 0; ks < 2; ks++)
            bfr[cb][ks] = *(const bf16x8*)&PT[(size_t)(wcol + cb*16 + r)*HD + ks*32 + g*8];

    #pragma unroll
    for(int ks = 0; ks < 2; ks++)
        #pragma unroll
        for(int rb = 0; rb < 2; rb++)
            #pragma unroll
            for(int cb = 0; cb < 4; cb++)
                acc[rb][cb] = __builtin_amdgcn_mfma_f32_16x16x32_bf16(
                                  afr[rb][ks], bfr[cb][ks], acc[rb][cb], 0, 0, 0);

    // C/D layout: col = lane&15 (=r), row = 4*(lane>>4)+reg (=4g+reg)
    #pragma unroll
    for(int rb = 0; rb < 2; rb++)
        #pragma unroll
        for(int cb = 0; cb < 4; cb++){
            unsigned short* Mp = M + (size_t)(nbase + rb*16 + g*4)*MCOLS + wcol + cb*16 + r;
            #pragma unroll
            for(int reg = 0; reg < 4; reg++)
                Mp[(size_t)reg*MCOLS] = f2bf(acc[rb][cb][reg]);
        }
}

// per-src block: stage M[s] in LDS, loop out-edges, scatter msg into agg via atomics. block=64
__global__ void k_msg_scatter(int c0, const int* __restrict__ rowptr, const int* __restrict__ elist,
                              const int* __restrict__ dstarr, const float* __restrict__ h1,
                              const unsigned short* __restrict__ M, float* __restrict__ agg){
    int s = c0 + blockIdx.x;
    int beg = rowptr[s], end = rowptr[s+1];
    if(beg == end) return;
    __shared__ uint4 s_Mv[MCOLS/8];               // 4160 u16 = 520 uint4
    __shared__ float s_h1[HD];
    unsigned short* s_M = (unsigned short*)s_Mv;
    int tid = threadIdx.x;                        // 64
    {
        const uint4* srcl = (const uint4*)(M + (size_t)(s - c0)*MCOLS);
        for(int it = tid; it < MCOLS/8; it += 64) s_Mv[it] = srcl[it];
    }
    __syncthreads();
    float bias = bf2f(s_M[HD*HD + tid]);
    for(int p = beg; p < end; p++){
        int e = elist[p];
        s_h1[tid] = h1[(size_t)e*HD + tid];
        __syncthreads();
        float a0 = 0, a1 = 0, a2 = 0, a3 = 0;
        #pragma unroll
        for(int k = 0; k < HD; k += 4){
            a0 += s_h1[k]   * bf2f(s_M[(k  )*HD + tid]);
            a1 += s_h1[k+1] * bf2f(s_M[(k+1)*HD + tid]);
            a2 += s_h1[k+2] * bf2f(s_M[(k+2)*HD + tid]);
            a3 += s_h1[k+3] * bf2f(s_M[(k+3)*HD + tid]);
        }
        float msg = (a0 + a1) + (a2 + a3) + bias;
        int d = dstarr[e];
        atomicAdd(&agg[(size_t)d*HD + tid], msg);
        __syncthreads();
    }
}

// m = relu(agg/counts + state @ Wroot^T + b_conv). block=64, grid=N
__global__ void k_m(const float* __restrict__ agg, const float* __restrict__ countsf,
                    const float* __restrict__ state, const float* __restrict__ wrT,
                    const float* __restrict__ bconv, float* __restrict__ mbuf){
    int d = blockIdx.x;
    int o = threadIdx.x;
    __shared__ float s_x[HD];
    s_x[o] = state[(size_t)d*HD + o];
    __syncthreads();
    float root = bconv[o];
    #pragma unroll 8
    for(int i = 0; i < HD; i++) root += s_x[i] * wrT[i*HD + o];
    float m = agg[(size_t)d*HD + o] / countsf[d] + root;
    mbuf[(size_t)d*HD + o] = m > 0.f ? m : 0.f;
}

// GRU cell, 4 nodes/block, block=192 (= 3h gate outputs)
__global__ void k_gru(const float* __restrict__ mbuf, const float* __restrict__ hprev,
                      const float* __restrict__ wTih, const float* __restrict__ wThh,
                      const float* __restrict__ b_ih, const float* __restrict__ b_hh,
                      float* __restrict__ hnew){
    int d0 = blockIdx.x * 4;
    int t = threadIdx.x;                          // 192
    __shared__ float s_m[4*HD], s_h[4*HD], s_gi[4*192], s_gh[4*192];
    for(int idx = t; idx < 4*HD; idx += 192){
        s_m[idx] = mbuf[(size_t)d0*HD + idx];
        s_h[idx] = hprev[(size_t)d0*HD + idx];
    }
    __syncthreads();
    float gi0 = b_ih[t], gi1 = gi0, gi2 = gi0, gi3 = gi0;
    float gh0 = b_hh[t], gh1 = gh0, gh2 = gh0, gh3 = gh0;
    #pragma unroll 4
    for(int i = 0; i < HD; i++){
        float wi = wTih[i*192 + t];
        float wh = wThh[i*192 + t];
        gi0 += s_m[i]*wi;      gh0 += s_h[i]*wh;
        gi1 += s_m[HD+i]*wi;   gh1 += s_h[HD+i]*wh;
        gi2 += s_m[2*HD+i]*wi; gh2 += s_h[2*HD+i]*wh;
        gi3 += s_m[3*HD+i]*wi; gh3 += s_h[3*HD+i]*wh;
    }
    s_gi[t] = gi0; s_gi[192+t] = gi1; s_gi[384+t] = gi2; s_gi[576+t] = gi3;
    s_gh[t] = gh0; s_gh[192+t] = gh1; s_gh[384+t] = gh2; s_gh[576+t] = gh3;
    __syncthreads();
    for(int idx = t; idx < 4*HD; idx += 192){
        int nl = idx >> 6, j = idx & 63;
        const float* gi = s_gi + nl*192;
        const float* gh = s_gh + nl*192;
        float r  = 1.f/(1.f + __expf(-(gi[j]      + gh[j])));
        float z  = 1.f/(1.f + __expf(-(gi[HD+j]   + gh[HD+j])));
        float nn = tanhf(gi[2*HD+j] + r*gh[2*HD+j]);
        hnew[(size_t)d0*HD + idx] = (1.f - z)*nn + z*s_h[idx];
    }
}

extern "C" void kernel_launch(void* const* d_in, const int* in_sizes, int n_in,
                              void* d_out, int out_size, void* d_ws, size_t ws_size,
                              hipStream_t stream){
    const float* x     = (const float*)d_in[0];
    const float* ea    = (const float*)d_in[1];
    const float* W1    = (const float*)d_in[2];
    const float* b1    = (const float*)d_in[3];
    const float* W2    = (const float*)d_in[4];
    const float* b2    = (const float*)d_in[5];
    const float* Wroot = (const float*)d_in[6];
    const float* bconv = (const float*)d_in[7];
    const float* w_ih  = (const float*)d_in[8];
    const float* w_hh  = (const float*)d_in[9];
    const float* b_ih  = (const float*)d_in[10];
    const float* b_hh  = (const float*)d_in[11];
    const int*   eidx  = (const int*)d_in[12];
    int N = in_sizes[0] / HD;
    int E = in_sizes[1] / ED;
    const int* srcarr = eidx;
    const int* dstarr = eidx + E;

    char* w = (char*)d_ws;
    size_t off = 0;
    auto alloc = [&](size_t bytes)->char*{
        char* p = w + off; off = (off + bytes + 255) & ~(size_t)255; return p;
    };
    int*   deg_src = (int*)alloc((size_t)N*4);
    int*   deg_dst = (int*)alloc((size_t)N*4);
    int*   rowptr  = (int*)alloc((size_t)(N+1)*4);
    int*   cursor  = (int*)alloc((size_t)N*4);
    int*   elist   = (int*)alloc((size_t)E*4);
    float* countsf = (float*)alloc((size_t)N*4);
    float* h1      = (float*)alloc((size_t)E*HD*4);
    unsigned short* PT  = (unsigned short*)alloc((size_t)MCOLS*HD*2);
    unsigned short* Abf = (unsigned short*)alloc((size_t)N*HD*2);
    float* wTih    = (float*)alloc((size_t)3*HD*HD*4);
    float* wThh    = (float*)alloc((size_t)3*HD*HD*4);
    float* wrT     = (float*)alloc((size_t)HD*HD*4);
    float* agg     = (float*)alloc((size_t)N*HD*4);
    float* mbuf    = (float*)alloc((size_t)N*HD*4);
    float* stA     = (float*)alloc((size_t)N*HD*4);
    float* stB     = (float*)alloc((size_t)N*HD*4);
    // remaining workspace -> bf16 M chunk (node-chunked if ws is small)
    size_t avail = (ws_size > off) ? ws_size - off : 0;
    long long Cll = (long long)(avail / ((size_t)MCOLS*2));
    int C = (Cll > N) ? N : (int)Cll;
    C &= ~31;
    if(C < 32) C = 32;
    unsigned short* M = (unsigned short*)(w + off);

    // ---- precompute ----
    hipLaunchKernelGGL(k_zero2, dim3((N+255)/256), dim3(256), 0, stream, deg_src, deg_dst, N);
    hipLaunchKernelGGL(k_deg,   dim3((E+255)/256), dim3(256), 0, stream, srcarr, dstarr, E, deg_src, deg_dst);
    hipLaunchKernelGGL(k_scan,  dim3(1), dim3(1024), 0, stream, deg_src, deg_dst, N, rowptr, cursor, countsf);
    hipLaunchKernelGGL(k_fill,  dim3((E+255)/256), dim3(256), 0, stream, srcarr, E, cursor, elist);
    hipLaunchKernelGGL(k_h1,    dim3((E+3)/4), dim3(256), 0, stream, ea, W1, b1, E, h1);
    hipLaunchKernelGGL(k_permT, dim3((MCOLS*HD+255)/256), dim3(256), 0, stream, W2, b2, PT);
    hipLaunchKernelGGL(k_wT,    dim3((3*HD*HD+255)/256), dim3(256), 0, stream, w_ih, w_hh, Wroot, wTih, wThh, wrT);

    // ---- 3 message-passing + GRU iterations ----
    const float* state = x;
    for(int it = 0; it < 3; ++it){
        hipLaunchKernelGGL(k_zerof, dim3((N*HD+255)/256), dim3(256), 0, stream, agg, N*HD);
        hipLaunchKernelGGL(k_cvtA,  dim3((N*HD/4+255)/256), dim3(256), 0, stream, state, Abf, N*HD);
        for(int c0 = 0; c0 < N; c0 += C){
            int cn = (N - c0 < C) ? (N - c0) : C;
            hipLaunchKernelGGL(k_gemm_mfma, dim3(KC, cn/32), dim3(64), 0, stream, Abf, PT, c0, M);
            hipLaunchKernelGGL(k_msg_scatter, dim3(cn), dim3(64), 0, stream,
                               c0, rowptr, elist, dstarr, h1, M, agg);
        }
        hipLaunchKernelGGL(k_m, dim3(N), dim3(64), 0, stream, agg, countsf, state, wrT, bconv, mbuf);
        float* outp = (it == 2) ? (float*)d_out : ((it == 0) ? stA : stB);
        hipLaunchKernelGGL(k_gru, dim3(N/4), dim3(192), 0, stream,
                           mbuf, state, wTih, wThh, b_ih, b_hh, outp);
        state = outp;
    }
}